// Round 13
// baseline (18.511 us; speedup 1.0000x reference)
//
#include <hip/hip_runtime.h>
#include <math.h>

// Van Rossum loss, SINGLE dispatch, 256 streaming blocks, fence-free finish.
//   W[t,j] = e^{(t-1023)/20} * e^{-j/20} / 20  (j<=t)
//   loss ~= C0 * mean_b sum_n g^2,  g_u = sum_{j<J} x_j e^{-j/20},
//   scale = C0/(20^2 * B),  C0 = 1/(1-e^{-0.1}).  J=96: err ~2e-3 << 1.375e-1.
// Reads 2 x 32 x 96 x 256 floats = 6.3 MB.
//
// Lessons applied: (R12) stream must be >=256 blocks wide; (R9/R10) no
// __threadfence in streaming blocks; (R11) monotonic ticket needs no init.
// New: block = (batch, 128B column-slice) covers ALL rows -> per-block output
// is a SCALAR. Scalar goes out via atomicExch (coherent store, overwritten
// each replay); exch ordered before the ticket by consuming its return value
// (vmcnt dependency + asm barrier); last-of-256 block reads the 256 partials
// with atomic reads and writes out[0] in a fixed lane order (deterministic).
// No fences, no init dispatch, no float-atomicAdd ordering variance.
//
// Layout: 256 blocks = (b, cg). Thread t: rowgroup rg=t>>3 (rows 3rg..3rg+2),
// col4 c4=t&7. Wave-load = 8 rows x 128B full lines. Per-thread weight
// e^{-3rg/20} via __expf; rows +1,+2 by constants. LDS 4KB + wave-0 fold.

#define B_DIM 32
#define T_DIM 1024
#define N_DIM 256
#define JROWS 96
#define NBLK 256

__global__ __launch_bounds__(256) void vr_one(
    const float* __restrict__ spike, const float* __restrict__ target,
    float* __restrict__ wsP, unsigned* __restrict__ wsCnt,
    float* __restrict__ out, float scale)
{
    int t  = threadIdx.x;
    int b  = blockIdx.x >> 3;       // batch
    int cg = blockIdx.x & 7;        // 128B column-slice (8 float4 cols)
    int rg = t >> 3;                // 0..31, rows 3rg..3rg+2
    int c4 = t & 7;                 // float4 col within slice

    const float e1 = 0.95122942f;   // e^{-1/20}
    const float e2 = 0.90483742f;   // e^{-2/20}
    float w0 = __expf(-0.15f * (float)rg);   // e^{-3rg/20}

    size_t base = ((size_t)(b * T_DIM + 3 * rg) * N_DIM)
                + (size_t)(cg * 32 + c4 * 4);
    const float4* sp = reinterpret_cast<const float4*>(spike + base);
    const float4* tg = reinterpret_cast<const float4*>(target + base);

    float4 s0 = sp[0],  s1 = sp[64],  s2 = sp[128];   // rows 3rg, +1, +2
    float4 t0 = tg[0],  t1 = tg[64],  t2 = tg[128];

    float4 y;
    y.x = w0 * ((s0.x - t0.x) + e1 * (s1.x - t1.x) + e2 * (s2.x - t2.x));
    y.y = w0 * ((s0.y - t0.y) + e1 * (s1.y - t1.y) + e2 * (s2.y - t2.y));
    y.z = w0 * ((s0.z - t0.z) + e1 * (s1.z - t1.z) + e2 * (s2.z - t2.z));
    y.w = w0 * ((s0.w - t0.w) + e1 * (s1.w - t1.w) + e2 * (s2.w - t2.w));

    __shared__ float4 sL[256];
    __shared__ int lastFlag;
    sL[t] = y;
    __syncthreads();

    if (t < 64) {
        int l8 = t >> 3, lc = t & 7;
        // sum 4 rowgroups per lane, then xor-fold over lane bits 3..5
        float4 g = make_float4(0.f, 0.f, 0.f, 0.f);
        #pragma unroll
        for (int k = 0; k < 4; ++k) {
            float4 v = sL[(l8 * 4 + k) * 8 + lc];
            g.x += v.x; g.y += v.y; g.z += v.z; g.w += v.w;
        }
        #pragma unroll
        for (int m = 8; m <= 32; m <<= 1) {
            g.x += __shfl_xor(g.x, m);
            g.y += __shfl_xor(g.y, m);
            g.z += __shfl_xor(g.z, m);
            g.w += __shfl_xor(g.w, m);
        }
        // g = full-column sums for col lc; square-sum across the 8 cols
        float c = (g.x * g.x + g.y * g.y) + (g.z * g.z + g.w * g.w);
        c += __shfl_xor(c, 1);
        c += __shfl_xor(c, 2);
        c += __shfl_xor(c, 4);

        if (t == 0) {
            float oldv = atomicExch(&wsP[blockIdx.x], c);   // coherent store
            asm volatile("" :: "v"(oldv) : "memory");       // order: exch done first
            unsigned old = atomicAdd(wsCnt, 1u);            // monotonic ticket
            lastFlag = ((old & 255u) == 255u) ? 1 : 0;
        }
    }
    __syncthreads();

    if (lastFlag && t < 64) {
        float v = 0.f;
        #pragma unroll
        for (int k = 0; k < 4; ++k)
            v += atomicAdd(&wsP[k * 64 + t], 0.0f);        // coherent read
        #pragma unroll
        for (int m = 1; m <= 32; m <<= 1)
            v += __shfl_xor(v, m);
        if (t == 0) out[0] = v * scale;
    }
}

extern "C" void kernel_launch(void* const* d_in, const int* in_sizes, int n_in,
                              void* d_out, int out_size, void* d_ws, size_t ws_size,
                              hipStream_t stream)
{
    (void)in_sizes; (void)n_in; (void)ws_size; (void)out_size;
    const float* spike  = (const float*)d_in[0];
    const float* target = (const float*)d_in[1];
    float* out = (float*)d_out;

    float*    wsP   = (float*)d_ws;                  // 256 floats (atomicExch'd)
    unsigned* wsCnt = (unsigned*)(wsP + NBLK);       // monotonic, never reset

    const double C0 = 1.0 / (1.0 - exp(-0.1));       // sum_k e^{-k/10}
    float scale = (float)(C0 / (400.0 * 32.0));      // /20^2, mean over B

    hipLaunchKernelGGL(vr_one, dim3(NBLK), dim3(256), 0, stream,
                       spike, target, wsP, wsCnt, out, scale);
}

// Round 14
// 10.114 us; speedup vs baseline: 1.8302x; 1.8302x over previous
//
#include <hip/hip_runtime.h>
#include <math.h>

// Van Rossum loss, SINGLE dispatch, wide stream, hierarchical fence-free finish.
//   W[t,j] = e^{(t-1023)/20} * e^{-j/20} / 20  (j<=t)
//   loss ~= C0 * mean_b sum_n g^2,  g = sum_{j<96} x_j e^{-j/20}
//   scale = C0/(20^2*B), C0 = 1/(1-e^{-0.1}); J=96 err ~1e-3 << 1.375e-1.
// Reads 2 x 32 x 96 x 256 floats = 6.3 MB (L2/L3-resident across replays).
//
// Lessons: (R12) stream >=256 blocks; (R9/R10) no __threadfence anywhere in
// the wide path; (R13) NEVER >64 same-line atomics -- its 256-deep ticket
// serialized ~5-6us. Fix: hierarchical rendezvous, max same-line depth = 32.
//   block: scalar c -> atomicExch wsP[bid] (256 distinct slots, garbage-immune)
//          -> per-batch ticket wsT[b] (32 lines, depth 8)
//   batch-last: reads 8 slots (coherent atomic reads), exch sum -> wsS[b]
//          -> global ticket gT (depth 32)
//   global-last: reads 32 wsS in fixed lane order -> out[0].
// Tickets are modular (old&mask) so ws garbage / no-init is fine; all
// value cells are exch-overwritten before any read. exch->ticket ordering
// via consuming the returned value (vmcnt dependency + asm barrier).

#define B_DIM 32
#define T_DIM 1024
#define N_DIM 256
#define NBLK 256

__global__ __launch_bounds__(256) void vr_one(
    const float* __restrict__ spike, const float* __restrict__ target,
    float* __restrict__ wsP, unsigned* __restrict__ wsT,
    float* __restrict__ wsS, unsigned* __restrict__ gT,
    float* __restrict__ out, float scale)
{
    int t  = threadIdx.x;
    int b  = blockIdx.x >> 3;       // batch
    int cg = blockIdx.x & 7;        // 128B column-slice (8 float4 cols)
    int rg = t >> 3;                // 0..31 -> rows 3rg..3rg+2
    int c4 = t & 7;                 // float4 col within slice

    const float e1 = 0.95122942f;   // e^{-1/20}
    const float e2 = 0.90483742f;   // e^{-2/20}
    float w0 = __expf(-0.15f * (float)rg);   // e^{-3rg/20}

    size_t base = ((size_t)(b * T_DIM + 3 * rg) * N_DIM)
                + (size_t)(cg * 32 + c4 * 4);
    const float4* sp = reinterpret_cast<const float4*>(spike + base);
    const float4* tg = reinterpret_cast<const float4*>(target + base);

    float4 s0 = sp[0], s1 = sp[64], s2 = sp[128];   // rows 3rg, +1, +2
    float4 t0 = tg[0], t1 = tg[64], t2 = tg[128];

    float4 y;
    y.x = w0 * ((s0.x - t0.x) + e1 * (s1.x - t1.x) + e2 * (s2.x - t2.x));
    y.y = w0 * ((s0.y - t0.y) + e1 * (s1.y - t1.y) + e2 * (s2.y - t2.y));
    y.z = w0 * ((s0.z - t0.z) + e1 * (s1.z - t1.z) + e2 * (s2.z - t2.z));
    y.w = w0 * ((s0.w - t0.w) + e1 * (s1.w - t1.w) + e2 * (s2.w - t2.w));

    __shared__ float4 sL[256];
    __shared__ int flagB, flagG;
    sL[t] = y;
    if (t == 0) { flagB = 0; flagG = 0; }
    __syncthreads();

    if (t < 64) {
        int l8 = t >> 3, lc = t & 7;
        float4 g = make_float4(0.f, 0.f, 0.f, 0.f);
        #pragma unroll
        for (int k = 0; k < 4; ++k) {
            float4 v = sL[(l8 * 4 + k) * 8 + lc];
            g.x += v.x; g.y += v.y; g.z += v.z; g.w += v.w;
        }
        #pragma unroll
        for (int m = 8; m <= 32; m <<= 1) {
            g.x += __shfl_xor(g.x, m);
            g.y += __shfl_xor(g.y, m);
            g.z += __shfl_xor(g.z, m);
            g.w += __shfl_xor(g.w, m);
        }
        float c = (g.x * g.x + g.y * g.y) + (g.z * g.z + g.w * g.w);
        c += __shfl_xor(c, 1);
        c += __shfl_xor(c, 2);
        c += __shfl_xor(c, 4);

        if (t == 0) {
            float ov = atomicExch(&wsP[blockIdx.x], c);     // distinct slot
            asm volatile("" :: "v"(ov) : "memory");          // exch before ticket
            unsigned o1 = atomicAdd(&wsT[b], 1u);            // depth-8 line
            flagB = ((o1 & 7u) == 7u) ? 1 : 0;               // modular: no init
        }
    }
    __syncthreads();

    if (flagB) {                    // batch-last block: fold batch b
        float bs = (t < 8) ? atomicAdd(&wsP[b * 8 + t], 0.0f) : 0.f;
        bs += __shfl_xor(bs, 1);
        bs += __shfl_xor(bs, 2);
        bs += __shfl_xor(bs, 4);
        if (t == 0) {
            float ov = atomicExch(&wsS[b], bs);              // distinct slot
            asm volatile("" :: "v"(ov) : "memory");
            unsigned o2 = atomicAdd(gT, 1u);                 // depth-32 line
            flagG = ((o2 & 31u) == 31u) ? 1 : 0;
        }
    }
    __syncthreads();

    if (flagG) {                    // global-last block: fold 32 batch sums
        float v = (t < B_DIM) ? atomicAdd(&wsS[t], 0.0f) : 0.f;
        #pragma unroll
        for (int m = 1; m <= 16; m <<= 1) v += __shfl_xor(v, m);
        if (t == 0) out[0] = v * scale;
    }
}

extern "C" void kernel_launch(void* const* d_in, const int* in_sizes, int n_in,
                              void* d_out, int out_size, void* d_ws, size_t ws_size,
                              hipStream_t stream)
{
    (void)in_sizes; (void)n_in; (void)ws_size; (void)out_size;
    const float* spike  = (const float*)d_in[0];
    const float* target = (const float*)d_in[1];
    float* out = (float*)d_out;

    float*    wsP = (float*)d_ws;                    // 256 slots (exch'd)
    unsigned* wsT = (unsigned*)(wsP + NBLK);         // 32 batch tickets (modular)
    float*    wsS = (float*)(wsT + B_DIM);           // 32 batch sums (exch'd)
    unsigned* gT  = (unsigned*)(wsS + B_DIM);        // global ticket (modular)

    const double C0 = 1.0 / (1.0 - exp(-0.1));       // sum_k e^{-k/10}
    float scale = (float)(C0 / (400.0 * 32.0));      // /20^2, mean over B

    hipLaunchKernelGGL(vr_one, dim3(NBLK), dim3(256), 0, stream,
                       spike, target, wsP, wsT, wsS, gT, out, scale);
}